// Round 3
// baseline (172.881 us; speedup 1.0000x reference)
//
#include <hip/hip_runtime.h>
#include <stdint.h>

#define NTOT 8192
#define NX   4096
#define DIM  256
#define NBJ  64                      // 8192/128 tiles per dimension
#define NBLK (NBJ*(NBJ+1)/2)         // 2080 upper-triangle tiles

typedef unsigned short u16;
typedef __attribute__((ext_vector_type(8))) short  bf16x8;
typedef __attribute__((ext_vector_type(4))) float  f32x4;

// ---- workspace layout (bytes) ----
// tot (fragment layout) : u16[8192*256] = 4,194,304
// sq   : float[8192] ; sqpart : float[1024] ; part : double[2080]
// c2   : float[4] ; colacc : float[32*256] ; cnt : uint[4]
#define OFF_TOT     0
#define OFF_SQ      4194304
#define OFF_SQPART  (OFF_SQ + 32768)
#define OFF_PART    (OFF_SQPART + 4096)
#define OFF_C2      (OFF_PART + 16640)
#define OFF_COLACC  (OFF_C2 + 16)
#define OFF_CNT     (OFF_COLACC + 32768)     // memset covers COLACC..CNT

__device__ __forceinline__ u16 f2bf(float f) {
  union { float f; unsigned int u; } v; v.f = f;
  unsigned int u = v.u;
  u += 0x7fffu + ((u >> 16) & 1u);           // round-to-nearest-even
  return (u16)(u >> 16);
}

// fragment-native layout: u16 offset = (row/16)*4096 + (k/8)*128 + (row%16)*8 + k%8
__device__ __forceinline__ void store_frag(u16* tot, int r, int c, float4 v) {
  ushort4 o;
  o.x = f2bf(v.x); o.y = f2bf(v.y); o.z = f2bf(v.z); o.w = f2bf(v.w);
  *(ushort4*)(tot + (size_t)(r >> 4) * 4096 + (c >> 3) * 128 + (r & 15) * 8 + (c & 7)) = o;
}

// ---- K1: prep. 1024 blocks x 256 threads; 8 rows/block (2 rows/wave).
// fp32->bf16 fragment layout, ||row||^2, column-sum partials (atomic into
// 32x256 groups), last block computes bandwidth -> c2.
__global__ __launch_bounds__(256) void k_prep(const float* __restrict__ x,
                                              const float* __restrict__ y,
                                              u16* __restrict__ tot,
                                              float* __restrict__ sq,
                                              float* __restrict__ sqpart,
                                              float* __restrict__ colacc,
                                              float* __restrict__ c2out,
                                              unsigned int* __restrict__ cnt) {
  const int tid = threadIdx.x, wave = tid >> 6, lane = tid & 63;
  const int h = lane & 31, rsel = lane >> 5;
  const int r = blockIdx.x * 8 + wave * 2 + rsel;
  const float* row = (r < NX) ? (x + (size_t)r * DIM) : (y + (size_t)(r - NX) * DIM);
  float4 v1 = ((const float4*)row)[h];        // cols 4h..4h+3
  float4 v2 = ((const float4*)row)[h + 32];   // cols 128+4h..
  store_frag(tot, r, h * 4, v1);
  store_frag(tot, r, 128 + h * 4, v2);

  float s = v1.x*v1.x + v1.y*v1.y + v1.z*v1.z + v1.w*v1.w
          + v2.x*v2.x + v2.y*v2.y + v2.z*v2.z + v2.w*v2.w;
  #pragma unroll
  for (int off = 16; off; off >>= 1) s += __shfl_down(s, off, 32);  // per-32-lane row group

  __shared__ float cpart[8][256];
  __shared__ float sred[8];
  const int slot = wave * 2 + rsel;
  if (h == 0) { sq[r] = s; sred[slot] = s; }
  ((float4*)cpart[slot])[h] = v1;
  ((float4*)cpart[slot])[h + 32] = v2;
  __syncthreads();
  float colp = 0.f;
  #pragma unroll
  for (int sl = 0; sl < 8; ++sl) colp += cpart[sl][tid];
  atomicAdd(&colacc[(blockIdx.x & 31) * 256 + tid], colp);
  if (tid == 0)
    sqpart[blockIdx.x] = sred[0]+sred[1]+sred[2]+sred[3]+sred[4]+sred[5]+sred[6]+sred[7];

  __shared__ int lastflag;
  __syncthreads();
  if (tid == 0) { __threadfence(); lastflag = (atomicAdd(cnt, 1u) == 1023u); }
  __syncthreads();
  if (!lastflag) return;
  __threadfence();

  __shared__ double red[256];
  double s1 = (double)sqpart[tid] + (double)sqpart[tid+256]
            + (double)sqpart[tid+512] + (double)sqpart[tid+768];
  red[tid] = s1; __syncthreads();
  for (int off = 128; off; off >>= 1) { if (tid < off) red[tid] += red[tid+off]; __syncthreads(); }
  const double S1 = red[0]; __syncthreads();
  double cs = 0.0;
  #pragma unroll
  for (int g = 0; g < 32; ++g) cs += (double)colacc[g * 256 + tid];
  red[tid] = cs * cs; __syncthreads();
  for (int off = 128; off; off >>= 1) { if (tid < off) red[tid] += red[tid+off]; __syncthreads(); }
  if (tid == 0) {
    const double CS2 = red[0];
    const double n = (double)NTOT;
    const double S = 2.0 * n * S1 - 2.0 * CS2;     // sum(L2); clip negligible
    double bw = S / (n * n - n);
    bw *= 0.25;                                     // / KERNEL_MUL^(KERNEL_NUM//2)
    c2out[0] = (float)(1.0 / (16.0 * bw * 0.6931471805599453));
  }
}

// ---- K2: gram + 5-kernel RBF + signed sum. NO LDS staging, NO barriers in
// the K-loop: fragments loaded directly from L2-resident fragment-layout tot.
// 2080 upper-triangle tiles x 256 threads (2x2 waves, 128x128 tile).
__global__ __launch_bounds__(256, 2) void k_main(const u16* __restrict__ tot,
                                                 const float* __restrict__ sq,
                                                 const float* __restrict__ c2p,
                                                 double* __restrict__ part,
                                                 unsigned int* __restrict__ cnt,
                                                 float* __restrict__ out) {
  const int tid = threadIdx.x, wave = tid >> 6, lane = tid & 63;
  const int quad = lane >> 4, l16 = lane & 15;

  const int idx = blockIdx.x;
  int bj = (int)((sqrtf(8.0f * (float)idx + 1.0f) - 1.0f) * 0.5f);
  while ((bj + 1) * (bj + 2) / 2 <= idx) ++bj;
  while (bj * (bj + 1) / 2 > idx) --bj;
  const int bi = idx - bj * (bj + 1) / 2;
  const int wm = wave >> 1, wn = wave & 1;

  const int off0 = quad * 128 + l16 * 8;     // within-chunk fragment offset (u16)
  const u16* Abase = tot + (size_t)(bi * 8 + wm * 4) * 4096 + off0;
  const u16* Bbase = tot + (size_t)(bj * 8 + wn * 4) * 4096 + off0;

  f32x4 acc[4][4];
  #pragma unroll
  for (int tm = 0; tm < 4; ++tm)
    #pragma unroll
    for (int tn = 0; tn < 4; ++tn) {
      acc[tm][tn][0] = 0.f; acc[tm][tn][1] = 0.f;
      acc[tm][tn][2] = 0.f; acc[tm][tn][3] = 0.f;
    }

  #pragma unroll
  for (int kb = 0; kb < 32; kb += 4) {       // 8 K-slices of 32
    bf16x8 af[4], bf[4];
    #pragma unroll
    for (int tm = 0; tm < 4; ++tm)
      af[tm] = *(const bf16x8*)(Abase + (size_t)tm * 4096 + kb * 128);
    #pragma unroll
    for (int tn = 0; tn < 4; ++tn)
      bf[tn] = *(const bf16x8*)(Bbase + (size_t)tn * 4096 + kb * 128);
    #pragma unroll
    for (int tm = 0; tm < 4; ++tm)
      #pragma unroll
      for (int tn = 0; tn < 4; ++tn)
        acc[tm][tn] = __builtin_amdgcn_mfma_f32_16x16x32_bf16(af[tm], bf[tn], acc[tm][tn], 0, 0, 0);
  }

  // ---- epilogue: L2 -> u + u^2 + u^4 + u^8 + u^16 ----
  const float c2 = c2p[0];
  const int gi0 = bi * 128 + wm * 64;
  const int gj0 = bj * 128 + wn * 64;
  float lsum = 0.0f;
  #pragma unroll
  for (int tn = 0; tn < 4; ++tn) {
    const float sqj = sq[gj0 + tn * 16 + l16];
    #pragma unroll
    for (int tm = 0; tm < 4; ++tm) {
      const f32x4 sqi = *(const f32x4*)&sq[gi0 + tm * 16 + quad * 4];
      const f32x4 a = acc[tm][tn];
      #pragma unroll
      for (int r = 0; r < 4; ++r) {
        float d2 = sqi[r] + sqj - 2.0f * a[r];
        d2 = fmaxf(d2, 0.0f);
        float u  = __builtin_amdgcn_exp2f(-d2 * c2);   // exp(-L2/(16bw))
        float u2 = u * u, u4 = u2 * u2, u8 = u4 * u4, u16v = u8 * u8;
        lsum += u + u2 + u4 + u8 + u16v;
      }
    }
  }
  float w = ((bi < 32) == (bj < 32)) ? 1.0f : -1.0f;   // XX/YY vs XY/YX
  if (bi != bj) w *= 2.0f;                             // symmetry weight

  #pragma unroll
  for (int off = 32; off; off >>= 1) lsum += __shfl_down(lsum, off, 64);
  __shared__ float wsum[4];
  __shared__ int lastflag;
  if (lane == 0) wsum[wave] = lsum;
  __syncthreads();
  if (tid == 0) {
    double tot2 = (double)wsum[0] + (double)wsum[1] + (double)wsum[2] + (double)wsum[3];
    part[idx] = tot2 * (double)w;
    __threadfence();
    lastflag = (atomicAdd(cnt, 1u) == (unsigned)(NBLK - 1));
  }
  __syncthreads();
  if (!lastflag) return;
  __threadfence();

  __shared__ double red[256];
  double s = 0.0;
  for (int i = tid; i < NBLK; i += 256) s += part[i];
  red[tid] = s; __syncthreads();
  for (int off = 128; off; off >>= 1) { if (tid < off) red[tid] += red[tid+off]; __syncthreads(); }
  if (tid == 0) out[0] = (float)(red[0] / ((double)NX * (double)NX));
}

extern "C" void kernel_launch(void* const* d_in, const int* in_sizes, int n_in,
                              void* d_out, int out_size, void* d_ws, size_t ws_size,
                              hipStream_t stream) {
  const float* x = (const float*)d_in[0];
  const float* y = (const float*)d_in[1];
  char* ws = (char*)d_ws;
  u16*    tot    = (u16*)(ws + OFF_TOT);
  float*  sq     = (float*)(ws + OFF_SQ);
  float*  sqp    = (float*)(ws + OFF_SQPART);
  double* part   = (double*)(ws + OFF_PART);
  float*  c2     = (float*)(ws + OFF_C2);
  float*  colacc = (float*)(ws + OFF_COLACC);
  unsigned int* cnt = (unsigned int*)(ws + OFF_CNT);
  float*  out    = (float*)d_out;

  hipMemsetAsync(ws + OFF_COLACC, 0, 32768 + 16, stream);  // colacc + both counters
  hipLaunchKernelGGL(k_prep, dim3(1024), dim3(256), 0, stream, x, y, tot, sq, sqp, colacc, c2, cnt);
  hipLaunchKernelGGL(k_main, dim3(NBLK), dim3(256), 0, stream, tot, sq, c2, part, cnt + 1, out);
}

// Round 4
// 166.932 us; speedup vs baseline: 1.0356x; 1.0356x over previous
//
#include <hip/hip_runtime.h>
#include <stdint.h>

#define NTOT 8192
#define NX   4096
#define DIM  256
#define NBJ  64                      // 8192/128 tiles per dimension
#define NBLK (NBJ*(NBJ+1)/2)         // 2080 upper-triangle tiles (= 8 * 260)

typedef unsigned short u16;
typedef __attribute__((ext_vector_type(8))) short  bf16x8;
typedef __attribute__((ext_vector_type(8))) short  short8;
typedef __attribute__((ext_vector_type(4))) float  f32x4;

// ---- workspace layout (bytes) ----
#define OFF_TOT     0                        // u16[8192*256] fragment layout = 4,194,304
#define OFF_SQ      4194304                  // float[8192]
#define OFF_SQPART  (OFF_SQ + 32768)         // float[512]
#define OFF_PART    (OFF_SQPART + 2048)      // double[2080]
#define OFF_C2      (OFF_PART + 16640)       // float[4]
#define OFF_COLACC  (OFF_C2 + 16)            // float[8*256]
#define OFF_CNT     (OFF_COLACC + 8192)      // uint[4]  (memset covers COLACC..CNT)

__device__ __forceinline__ u16 f2bf(float f) {
  union { float f; unsigned int u; } v; v.f = f;
  unsigned int u = v.u;
  u += 0x7fffu + ((u >> 16) & 1u);           // round-to-nearest-even
  return (u16)(u >> 16);
}

// fragment layout: u16 offset = (r/16)*4096 + (k/8)*128 + (r%16)*8 + (k%8)

// ---- K1: prep. 512 blocks x 256; block = 16 rows (one fragment chunk).
// Coalesced float4 reads -> LDS bounce (fragment order) -> coalesced 16B
// global writes. Row norms, column sums; last block computes bandwidth->c2.
__global__ __launch_bounds__(256) void k_prep(const float* __restrict__ x,
                                              const float* __restrict__ y,
                                              u16* __restrict__ tot,
                                              float* __restrict__ sq,
                                              float* __restrict__ sqpart,
                                              float* __restrict__ colacc,
                                              float* __restrict__ c2out,
                                              unsigned int* __restrict__ cnt) {
  __shared__ u16   tile[4096];      // one 16-row fragment chunk image
  __shared__ float colLDS[256];
  __shared__ float sred[16];
  const int t  = threadIdx.x;
  const int rr = t >> 4;            // row within chunk (0..15)
  const int cg = t & 15;            // 16-col group
  const int r0 = blockIdx.x * 16;
  const int r  = r0 + rr;

  colLDS[t] = 0.f;
  __syncthreads();

  const float* row = (r < NX) ? (x + (size_t)r * DIM) : (y + (size_t)(r - NX) * DIM);
  const float4* rp = (const float4*)row + cg * 4;
  const float4 p0 = rp[0], p1 = rp[1], p2 = rp[2], p3 = rp[3];

  // bf16 convert -> LDS in fragment-chunk order: o(r,c) = (c>>3)*128 + rr*8 + (c&7)
  short8 h0, h1;
  h0[0]=(short)f2bf(p0.x); h0[1]=(short)f2bf(p0.y); h0[2]=(short)f2bf(p0.z); h0[3]=(short)f2bf(p0.w);
  h0[4]=(short)f2bf(p1.x); h0[5]=(short)f2bf(p1.y); h0[6]=(short)f2bf(p1.z); h0[7]=(short)f2bf(p1.w);
  h1[0]=(short)f2bf(p2.x); h1[1]=(short)f2bf(p2.y); h1[2]=(short)f2bf(p2.z); h1[3]=(short)f2bf(p2.w);
  h1[4]=(short)f2bf(p3.x); h1[5]=(short)f2bf(p3.y); h1[6]=(short)f2bf(p3.z); h1[7]=(short)f2bf(p3.w);
  *(short8*)&tile[cg * 256 + rr * 8]       = h0;   // cols cg*16+0..7
  *(short8*)&tile[cg * 256 + 128 + rr * 8] = h1;   // cols cg*16+8..15

  // column partials (LDS fp32 atomics; 16 rows collide per column - cheap)
  atomicAdd(&colLDS[cg*16+ 0], p0.x); atomicAdd(&colLDS[cg*16+ 1], p0.y);
  atomicAdd(&colLDS[cg*16+ 2], p0.z); atomicAdd(&colLDS[cg*16+ 3], p0.w);
  atomicAdd(&colLDS[cg*16+ 4], p1.x); atomicAdd(&colLDS[cg*16+ 5], p1.y);
  atomicAdd(&colLDS[cg*16+ 6], p1.z); atomicAdd(&colLDS[cg*16+ 7], p1.w);
  atomicAdd(&colLDS[cg*16+ 8], p2.x); atomicAdd(&colLDS[cg*16+ 9], p2.y);
  atomicAdd(&colLDS[cg*16+10], p2.z); atomicAdd(&colLDS[cg*16+11], p2.w);
  atomicAdd(&colLDS[cg*16+12], p3.x); atomicAdd(&colLDS[cg*16+13], p3.y);
  atomicAdd(&colLDS[cg*16+14], p3.z); atomicAdd(&colLDS[cg*16+15], p3.w);

  // row-norm partial; reduce across the 16 lanes of this row group
  float s = p0.x*p0.x + p0.y*p0.y + p0.z*p0.z + p0.w*p0.w
          + p1.x*p1.x + p1.y*p1.y + p1.z*p1.z + p1.w*p1.w
          + p2.x*p2.x + p2.y*p2.y + p2.z*p2.z + p2.w*p2.w
          + p3.x*p3.x + p3.y*p3.y + p3.z*p3.z + p3.w*p3.w;
  #pragma unroll
  for (int k = 8; k; k >>= 1) s += __shfl_down(s, k, 64);
  if (cg == 0) { sq[r] = s; sred[rr] = s; }
  __syncthreads();

  // coalesced 16B writes of the chunk (4096 u16 = 2 stores/thread)
  u16* chunk = tot + (size_t)blockIdx.x * 4096;
  *(uint4*)(chunk + t * 8)        = *(const uint4*)&tile[t * 8];
  *(uint4*)(chunk + 2048 + t * 8) = *(const uint4*)&tile[2048 + t * 8];

  atomicAdd(&colacc[(blockIdx.x & 7) * 256 + t], colLDS[t]);
  if (t == 0) {
    float ss = 0.f;
    #pragma unroll
    for (int i = 0; i < 16; ++i) ss += sred[i];
    sqpart[blockIdx.x] = ss;
  }

  __shared__ int lastflag;
  __syncthreads();
  if (t == 0) { __threadfence(); lastflag = (atomicAdd(cnt, 1u) == 511u); }
  __syncthreads();
  if (!lastflag) return;
  __threadfence();

  __shared__ double red[256];
  red[t] = (double)sqpart[t] + (double)sqpart[t + 256];
  __syncthreads();
  for (int off = 128; off; off >>= 1) { if (t < off) red[t] += red[t+off]; __syncthreads(); }
  const double S1 = red[0]; __syncthreads();
  double cs = 0.0;
  #pragma unroll
  for (int g = 0; g < 8; ++g) cs += (double)colacc[g * 256 + t];
  red[t] = cs * cs; __syncthreads();
  for (int off = 128; off; off >>= 1) { if (t < off) red[t] += red[t+off]; __syncthreads(); }
  if (t == 0) {
    const double CS2 = red[0];
    const double n = (double)NTOT;
    const double S = 2.0 * n * S1 - 2.0 * CS2;     // sum(L2); clip negligible
    double bw = S / (n * n - n);
    bw *= 0.25;                                     // / KERNEL_MUL^(KERNEL_NUM//2)
    c2out[0] = (float)(1.0 / (16.0 * bw * 0.6931471805599453));
  }
}

__device__ __forceinline__ void ldset(const u16* Ab, const u16* Bb, int it,
                                      bf16x8* a, bf16x8* b) {
  #pragma unroll
  for (int tm = 0; tm < 4; ++tm)
    a[tm] = *(const bf16x8*)(Ab + (size_t)tm * 4096 + (size_t)it * 512);
  #pragma unroll
  for (int tn = 0; tn < 4; ++tn)
    b[tn] = *(const bf16x8*)(Bb + (size_t)tn * 4096 + (size_t)it * 512);
}

// ---- K2: gram + 5-kernel RBF + signed sum. No LDS staging/barriers.
// XCD-banded tile map: blockIdx%8 -> XCD, each XCD gets a contiguous
// triangular band (260 tiles) so its working set stays in its own L2.
// Depth-2 software pipeline on fragment loads.
__global__ __launch_bounds__(256, 2) void k_main(const u16* __restrict__ tot,
                                                 const float* __restrict__ sq,
                                                 const float* __restrict__ c2p,
                                                 double* __restrict__ part,
                                                 unsigned int* __restrict__ cnt,
                                                 float* __restrict__ out) {
  const int tid = threadIdx.x, wave = tid >> 6, lane = tid & 63;
  const int quad = lane >> 4, l16 = lane & 15;

  const int xcd = blockIdx.x & 7;
  const int g   = 260 * xcd + (blockIdx.x >> 3);   // global triangular index
  int bj = (int)((sqrtf(8.0f * (float)g + 1.0f) - 1.0f) * 0.5f);
  while ((bj + 1) * (bj + 2) / 2 <= g) ++bj;
  while (bj * (bj + 1) / 2 > g) --bj;
  const int bi = g - bj * (bj + 1) / 2;
  const int wm = wave >> 1, wn = wave & 1;

  const int off0 = quad * 128 + l16 * 8;
  const u16* Ab = tot + (size_t)(bi * 8 + wm * 4) * 4096 + off0;
  const u16* Bb = tot + (size_t)(bj * 8 + wn * 4) * 4096 + off0;

  f32x4 acc[4][4];
  #pragma unroll
  for (int tm = 0; tm < 4; ++tm)
    #pragma unroll
    for (int tn = 0; tn < 4; ++tn) {
      acc[tm][tn][0] = 0.f; acc[tm][tn][1] = 0.f;
      acc[tm][tn][2] = 0.f; acc[tm][tn][3] = 0.f;
    }

  bf16x8 a[3][4], b[3][4];
  ldset(Ab, Bb, 0, a[0], b[0]);
  ldset(Ab, Bb, 1, a[1], b[1]);
  #pragma unroll
  for (int it = 0; it < 8; ++it) {
    const int cur = it % 3;
    if (it < 6) ldset(Ab, Bb, it + 2, a[(it + 2) % 3], b[(it + 2) % 3]);
    #pragma unroll
    for (int tm = 0; tm < 4; ++tm)
      #pragma unroll
      for (int tn = 0; tn < 4; ++tn)
        acc[tm][tn] = __builtin_amdgcn_mfma_f32_16x16x32_bf16(a[cur][tm], b[cur][tn], acc[tm][tn], 0, 0, 0);
  }

  // ---- epilogue: L2 -> u + u^2 + u^4 + u^8 + u^16 ----
  const float c2 = c2p[0];
  const int gi0 = bi * 128 + wm * 64;
  const int gj0 = bj * 128 + wn * 64;
  float lsum = 0.0f;
  #pragma unroll
  for (int tn = 0; tn < 4; ++tn) {
    const float sqj = sq[gj0 + tn * 16 + l16];
    #pragma unroll
    for (int tm = 0; tm < 4; ++tm) {
      const f32x4 sqi = *(const f32x4*)&sq[gi0 + tm * 16 + quad * 4];
      const f32x4 av = acc[tm][tn];
      #pragma unroll
      for (int r = 0; r < 4; ++r) {
        float d2 = sqi[r] + sqj - 2.0f * av[r];
        d2 = fmaxf(d2, 0.0f);
        float u  = __builtin_amdgcn_exp2f(-d2 * c2);   // exp(-L2/(16bw))
        float u2 = u * u, u4 = u2 * u2, u8 = u4 * u4, u16v = u8 * u8;
        lsum += u + u2 + u4 + u8 + u16v;
      }
    }
  }
  float w = ((bi < 32) == (bj < 32)) ? 1.0f : -1.0f;   // XX/YY vs XY/YX
  if (bi != bj) w *= 2.0f;                             // symmetry weight

  #pragma unroll
  for (int off = 32; off; off >>= 1) lsum += __shfl_down(lsum, off, 64);
  __shared__ float wsum[4];
  __shared__ int lastflag;
  if (lane == 0) wsum[wave] = lsum;
  __syncthreads();
  if (tid == 0) {
    double tsum = (double)wsum[0] + (double)wsum[1] + (double)wsum[2] + (double)wsum[3];
    part[g] = tsum * (double)w;
    __threadfence();
    lastflag = (atomicAdd(cnt, 1u) == (unsigned)(NBLK - 1));
  }
  __syncthreads();
  if (!lastflag) return;
  __threadfence();

  __shared__ double red[256];
  double s = 0.0;
  for (int i = tid; i < NBLK; i += 256) s += part[i];
  red[tid] = s; __syncthreads();
  for (int off = 128; off; off >>= 1) { if (tid < off) red[tid] += red[tid+off]; __syncthreads(); }
  if (tid == 0) out[0] = (float)(red[0] / ((double)NX * (double)NX));
}

extern "C" void kernel_launch(void* const* d_in, const int* in_sizes, int n_in,
                              void* d_out, int out_size, void* d_ws, size_t ws_size,
                              hipStream_t stream) {
  const float* x = (const float*)d_in[0];
  const float* y = (const float*)d_in[1];
  char* ws = (char*)d_ws;
  u16*    tot    = (u16*)(ws + OFF_TOT);
  float*  sq     = (float*)(ws + OFF_SQ);
  float*  sqp    = (float*)(ws + OFF_SQPART);
  double* part   = (double*)(ws + OFF_PART);
  float*  c2     = (float*)(ws + OFF_C2);
  float*  colacc = (float*)(ws + OFF_COLACC);
  unsigned int* cnt = (unsigned int*)(ws + OFF_CNT);
  float*  out    = (float*)d_out;

  hipMemsetAsync(ws + OFF_COLACC, 0, 8192 + 16, stream);   // colacc + counters
  hipLaunchKernelGGL(k_prep, dim3(512),  dim3(256), 0, stream, x, y, tot, sq, sqp, colacc, c2, cnt);
  hipLaunchKernelGGL(k_main, dim3(NBLK), dim3(256), 0, stream, tot, sq, c2, part, cnt + 1, out);
}